// Round 5
// baseline (9652.573 us; speedup 1.0000x reference)
//
#include <hip/hip_runtime.h>
#include <math.h>

#define TN 1024
#define HH 512
#define BB 256
#define NTHR 576          // 8 GEMV waves + 1 service wave

#define OFF_KEYS 0L
#define OFF_PRS  524288L
#define OFF_HS   1572864L
#define OFF_TM   135790592L

typedef float f32x4 __attribute__((ext_vector_type(4)));
typedef _Float16 f16x2 __attribute__((ext_vector_type(2)));

__device__ __forceinline__ float sigm(float x) { return 1.0f / (1.0f + expf(-x)); }

__device__ __forceinline__ float dot2(unsigned wu, unsigned hu, float c) {
#if __has_builtin(__builtin_amdgcn_fdot2)
    return __builtin_amdgcn_fdot2(__builtin_bit_cast(f16x2, wu),
                                  __builtin_bit_cast(f16x2, hu), c, false);
#else
    const f16x2 w2 = __builtin_bit_cast(f16x2, wu);
    const f16x2 h2 = __builtin_bit_cast(f16x2, hu);
    return fmaf((float)w2.y, (float)h2.y, fmaf((float)w2.x, (float)h2.x, c));
#endif
}

// ---- pre-kernel: convert w_rec (512x512 f32) to fp16 in d_ws ----
__global__ __launch_bounds__(256) void conv_fp16(const float* __restrict__ w,
                                                 _Float16* __restrict__ o) {
    const int i = (blockIdx.x * 256 + threadIdx.x) * 4;
    const f32x4 v = *(const f32x4*)(w + i);
    _Float16 r[4];
    #pragma unroll
    for (int k = 0; k < 4; ++k) r[k] = (_Float16)v[k];   // v_cvt_f16_f32 (RNE)
    *(unsigned long long*)(o + i) = *(const unsigned long long*)r;
}

__global__ __launch_bounds__(NTHR) void rnn_fused(
    const float* __restrict__ in,
    const float* __restrict__ w_in, const float* __restrict__ b_in,
    const _Float16* __restrict__ whf, const float* __restrict__ b_rec,
    const float* __restrict__ w_key, const float* __restrict__ b_key,
    const float* __restrict__ z,
    float* __restrict__ out)
{
    __shared__ __align__(16) _Float16 hsh16[HH];     // h_{t-1} packed fp16 (1 KB)
    __shared__ __align__(16) float tbuf[2][HH][17];  // hs 16-step tiles, padded (68 KB)
    __shared__ __align__(16) float keysT[2][2][16];
    __shared__ __align__(16) float prsT[2][4][16];
    __shared__ __align__(16) float tmT[2][16];
    __shared__ float wi_sh[HH][6];
    __shared__ float bsum[HH];
    __shared__ float wk2[2][HH];
    __shared__ float inp6[8];
    __shared__ float kred[8][2];

    const int tid = threadIdx.x;
    const int bb  = blockIdx.x;           // one batch per block
    const int wv  = tid >> 6;             // 0..8
    const int ln  = tid & 63;
    const int qd  = tid >> 2;             // quad id: rows qd*4..+3 (tid<512)
    const int q   = tid & 3;
    const float* inb = in + (long)bb * 8 * TN;

    // ---------------- init ----------------
    if (tid < 256) {
        hsh16[tid] = (_Float16)0.0f; hsh16[tid + 256] = (_Float16)0.0f;
        tbuf[0][tid][0] = 0.0f; tbuf[0][tid + 256][0] = 0.0f;
        bsum[tid]       = b_in[tid]       + b_rec[tid];
        bsum[tid + 256] = b_in[tid + 256] + b_rec[tid + 256];
        wk2[0][tid] = w_key[tid];           wk2[0][tid + 256] = w_key[tid + 256];
        wk2[1][tid] = w_key[HH + tid];      wk2[1][tid + 256] = w_key[HH + tid + 256];
        #pragma unroll
        for (int c = 0; c < 6; ++c) {
            wi_sh[tid][c]       = w_in[tid * 6 + c];
            wi_sh[tid + 256][c] = w_in[(tid + 256) * 6 + c];
        }
        // tm_modified[bb, 0, :] = tm1
        f32x4 v = *(const f32x4*)(inb + 6 * TN + tid * 4);
        __builtin_nontemporal_store(v, (f32x4*)(out + OFF_TM + (long)bb * 2 * TN + tid * 4));
    }
    if (tid == 512) {
        keysT[0][0][0] = 0.0f; keysT[0][1][0] = 0.0f;
        prsT[0][0][0] = 0.0f; prsT[0][1][0] = 0.0f;
        prsT[0][2][0] = 0.0f; prsT[0][3][0] = 0.0f;
        tmT[0][0] = inb[7 * TN];            // tm2[:,0]
    }
    // argmax(tm1) first-occurrence — service wave
    int idxm = 0;
    if (wv == 8) {
        const float* tm1p = inb + 6 * TN;
        float bv = -3.0e38f; int bi = 0;
        for (int i = 0; i < 16; ++i) {
            int tt = i * 64 + ln;
            float v = tm1p[tt];
            if (v > bv) { bv = v; bi = tt; }
        }
        for (int m = 1; m < 64; m <<= 1) {
            float ov = __shfl_xor(bv, m);
            int   oi = __shfl_xor(bi, m);
            if (ov > bv || (ov == bv && oi < bi)) { bv = ov; bi = oi; }
        }
        idxm = bi;
    }
    float kh = 1.0f, off = 0.0f;
    int side_pre = 1;
    __syncthreads();

    // ---------------- time loop ----------------
    for (int t = 1; t < TN; ++t) {
        const int tile = (t >> 4) & 1, sl = t & 15;
        float s = 0.0f;

        if (tid < 512) {
            // ---- GEMV rows qd*4..+3, fp16 dot2, K-split 4 lanes x 8 ----
            float acc[4] = {0.f, 0.f, 0.f, 0.f};
            const _Float16* wbase = whf + (long)(qd * 4) * HH + q * 8;
            #pragma unroll
            for (int kk = 0; kk < 16; ++kk) {
                const uint4 hu = *(const uint4*)&hsh16[kk * 32 + q * 8];
                #pragma unroll
                for (int r = 0; r < 4; ++r) {
                    const uint4 wu = *(const uint4*)(wbase + (long)r * HH + kk * 32);
                    acc[r] = dot2(wu.x, hu.x, acc[r]);
                    acc[r] = dot2(wu.y, hu.y, acc[r]);
                    acc[r] = dot2(wu.z, hu.z, acc[r]);
                    acc[r] = dot2(wu.w, hu.w, acc[r]);
                }
            }
            // distributing 4-lane reduce: lane q ends with row qd*4+q
            const bool qb0 = (q & 1), qb1 = (q & 2);
            float a0 = (qb0 ? acc[1] : acc[0]) + __shfl_xor(qb0 ? acc[0] : acc[1], 1, 4);
            float a1 = (qb0 ? acc[3] : acc[2]) + __shfl_xor(qb0 ? acc[2] : acc[3], 1, 4);
            s = (qb1 ? a1 : a0) + __shfl_xor(qb1 ? a0 : a1, 2, 4);
        } else if (tid == 512) {
            // ---- keys of t-1, then stage(t) ----
            if (t > 1) {
                float k0 = 0.f, k1 = 0.f;
                #pragma unroll
                for (int w = 0; w < 8; ++w) { k0 += kred[w][0]; k1 += kred[w][1]; }
                const float key0 = sigm(k0 + b_key[0]);
                const float key1 = sigm(k1 + b_key[1]);
                const int pt = t - 1;
                keysT[(pt >> 4) & 1][0][pt & 15] = key0;
                keysT[(pt >> 4) & 1][1][pt & 15] = key1;
                kh = key0;
            }
            const float ap0 = inb[t],          ap1 = inb[TN + t];
            const float a0  = inb[2 * TN + t], a1  = inb[3 * TN + t];
            const float a2  = inb[4 * TN + t], a3  = inb[5 * TN + t];
            const float t1  = inb[6 * TN + t], t2o = inb[7 * TN + t];
            const float zt  = z[(long)(t - 1) * BB + bb];
            const int side  = (kh > 0.5f);
            const float asum0 = a0 * kh + a2 * (1.0f - kh);
            const float asum1 = a1 * kh + a3 * (1.0f - kh);
            const int closer1  = (fabsf(ap0 - t1) <= fabsf(ap1 - t1));
            const int done     = (t > idxm);
            const int switched = ((side != side_pre) && done && (side != closer1));
            const float t2c = t2o + off;
            if (switched) off += zt * fabsf(0.05f * t2c);
            const float t2e = t2o + off;
            side_pre = side;
            float u0 = (t1 - ap0) / (0.15f * ap0);      float pr10 = (t1 == 0.0f)  ? 0.0f : u0 * u0;
            float u1 = (t1 - ap1) / (0.15f * ap1);      float pr11 = (t1 == 0.0f)  ? 0.0f : u1 * u1;
            float u2 = (t2e - asum0) / (0.15f * asum0); float pr20 = (t2e == 0.0f) ? 0.0f : u2 * u2;
            float u3 = (t2e - asum1) / (0.15f * asum1); float pr21 = (t2e == 0.0f) ? 0.0f : u3 * u3;
            prsT[tile][0][sl] = pr10; prsT[tile][1][sl] = pr11;
            prsT[tile][2][sl] = pr20; prsT[tile][3][sl] = pr21;
            tmT[tile][sl] = t2e;
            inp6[0] = ap0; inp6[1] = ap1; inp6[2] = asum0;
            inp6[3] = asum1; inp6[4] = t1; inp6[5] = t2e;
        }
        __syncthreads();   // B: GEMV h-reads done; inp6 ready

        if (tid < 512) {
            // ---- finalize row j = qd*4+q ----
            const int j = qd * 4 + q;
            float sm = s + bsum[j]
                     + wi_sh[j][0] * inp6[0] + wi_sh[j][1] * inp6[1] + wi_sh[j][2] * inp6[2]
                     + wi_sh[j][3] * inp6[3] + wi_sh[j][4] * inp6[4] + wi_sh[j][5] * inp6[5];
            const float h = tanhf(sm);
            hsh16[j] = (_Float16)h;
            tbuf[tile][j][sl] = h;
            float ka0 = h * wk2[0][j];
            float ka1 = h * wk2[1][j];
            #pragma unroll
            for (int m = 1; m < 64; m <<= 1) { ka0 += __shfl_xor(ka0, m); ka1 += __shfl_xor(ka1, m); }
            if (ln == 0) { kred[wv][0] = ka0; kred[wv][1] = ka1; }
        } else if ((t & 15) == 0) {
            // ---- service wave: flush previous 16-step tile ----
            const int f = tile ^ 1;
            const int t0 = t - 16;
            if (ln < 8) {
                const int ch = ln >> 2, q4 = ln & 3;
                __builtin_nontemporal_store(*(const f32x4*)&keysT[f][ch][q4 * 4],
                    (f32x4*)(out + OFF_KEYS + (long)bb * 2 * TN + ch * TN + t0 + q4 * 4));
            } else if (ln < 24) {
                const int ix = ln - 8, ch = ix >> 2, q4 = ix & 3;
                __builtin_nontemporal_store(*(const f32x4*)&prsT[f][ch][q4 * 4],
                    (f32x4*)(out + OFF_PRS + (long)bb * 4 * TN + ch * TN + t0 + q4 * 4));
            } else if (ln < 28) {
                const int q4 = ln - 24;
                __builtin_nontemporal_store(*(const f32x4*)&tmT[f][q4 * 4],
                    (f32x4*)(out + OFF_TM + (long)bb * 2 * TN + TN + t0 + q4 * 4));
            }
            #pragma unroll
            for (int k2 = 0; k2 < 8; ++k2) {
                const int j = ln + 64 * k2;
                const float* tr = &tbuf[f][j][0];
                #pragma unroll
                for (int c = 0; c < 4; ++c) {
                    f32x4 v;
                    v.x = tr[c * 4]; v.y = tr[c * 4 + 1]; v.z = tr[c * 4 + 2]; v.w = tr[c * 4 + 3];
                    __builtin_nontemporal_store(v,
                        (f32x4*)(out + OFF_HS + ((long)bb * HH + j) * TN + t0 + c * 4));
                }
            }
        }
        __syncthreads();   // D: hsh16/kred/tbuf visible for next iteration
    }

    // ---------------- epilogue ----------------
    if (tid == 512) {
        float k0 = 0.f, k1 = 0.f;
        #pragma unroll
        for (int w = 0; w < 8; ++w) { k0 += kred[w][0]; k1 += kred[w][1]; }
        keysT[1][0][15] = sigm(k0 + b_key[0]);
        keysT[1][1][15] = sigm(k1 + b_key[1]);
    }
    __syncthreads();
    if (wv == 8) {
        const int f = 1, t0 = TN - 16;
        if (ln < 8) {
            const int ch = ln >> 2, q4 = ln & 3;
            __builtin_nontemporal_store(*(const f32x4*)&keysT[f][ch][q4 * 4],
                (f32x4*)(out + OFF_KEYS + (long)bb * 2 * TN + ch * TN + t0 + q4 * 4));
        } else if (ln < 24) {
            const int ix = ln - 8, ch = ix >> 2, q4 = ix & 3;
            __builtin_nontemporal_store(*(const f32x4*)&prsT[f][ch][q4 * 4],
                (f32x4*)(out + OFF_PRS + (long)bb * 4 * TN + ch * TN + t0 + q4 * 4));
        } else if (ln < 28) {
            const int q4 = ln - 24;
            __builtin_nontemporal_store(*(const f32x4*)&tmT[f][q4 * 4],
                (f32x4*)(out + OFF_TM + (long)bb * 2 * TN + TN + t0 + q4 * 4));
        }
        #pragma unroll
        for (int k2 = 0; k2 < 8; ++k2) {
            const int j = ln + 64 * k2;
            const float* tr = &tbuf[f][j][0];
            #pragma unroll
            for (int c = 0; c < 4; ++c) {
                f32x4 v;
                v.x = tr[c * 4]; v.y = tr[c * 4 + 1]; v.z = tr[c * 4 + 2]; v.w = tr[c * 4 + 3];
                __builtin_nontemporal_store(v,
                    (f32x4*)(out + OFF_HS + ((long)bb * HH + j) * TN + t0 + c * 4));
            }
        }
    }
}

extern "C" void kernel_launch(void* const* d_in, const int* in_sizes, int n_in,
                              void* d_out, int out_size, void* d_ws, size_t ws_size,
                              hipStream_t stream) {
    (void)in_sizes; (void)n_in; (void)out_size; (void)ws_size;
    const float* in    = (const float*)d_in[0];
    const float* w_in  = (const float*)d_in[1];
    const float* b_in  = (const float*)d_in[2];
    const float* w_rec = (const float*)d_in[3];
    const float* b_rec = (const float*)d_in[4];
    const float* w_key = (const float*)d_in[5];
    const float* b_key = (const float*)d_in[6];
    const float* z     = (const float*)d_in[7];
    float* out = (float*)d_out;
    _Float16* whf = (_Float16*)d_ws;   // 512 KB scratch

    hipLaunchKernelGGL(conv_fp16, dim3(HH * HH / 1024), dim3(256), 0, stream, w_rec, whf);
    hipLaunchKernelGGL(rnn_fused, dim3(BB), dim3(NTHR), 0, stream,
                       in, w_in, b_in, whf, b_rec, w_key, b_key, z, out);
}

// Round 6
// 6767.506 us; speedup vs baseline: 1.4263x; 1.4263x over previous
//
#include <hip/hip_runtime.h>
#include <math.h>

#define TN 1024
#define HH 512
#define BB 256
#define NTHR 1024        // 16 waves: rows x K-halves

#define OFF_KEYS 0L
#define OFF_PRS  524288L
#define OFF_HS   1572864L
#define OFF_TM   135790592L

typedef float f32x4 __attribute__((ext_vector_type(4)));
typedef _Float16 f16x2 __attribute__((ext_vector_type(2)));

__device__ __forceinline__ float sigm(float x) { return 1.0f / (1.0f + expf(-x)); }

__device__ __forceinline__ float dot2(unsigned wu, unsigned hu, float c) {
#if __has_builtin(__builtin_amdgcn_fdot2)
    return __builtin_amdgcn_fdot2(__builtin_bit_cast(f16x2, wu),
                                  __builtin_bit_cast(f16x2, hu), c, false);
#else
    const f16x2 w2 = __builtin_bit_cast(f16x2, wu);
    const f16x2 h2 = __builtin_bit_cast(f16x2, hu);
    return fmaf((float)w2.y, (float)h2.y, fmaf((float)w2.x, (float)h2.x, c));
#endif
}

// ---- pre-kernel: convert w_rec (512x512 f32) to fp16 in d_ws ----
__global__ __launch_bounds__(256) void conv_fp16(const float* __restrict__ w,
                                                 _Float16* __restrict__ o) {
    const int i = (blockIdx.x * 256 + threadIdx.x) * 4;
    const f32x4 v = *(const f32x4*)(w + i);
    _Float16 r[4];
    #pragma unroll
    for (int k = 0; k < 4; ++k) r[k] = (_Float16)v[k];   // RNE
    *(unsigned long long*)(o + i) = *(const unsigned long long*)r;
}

__global__ __launch_bounds__(NTHR) void rnn_fused(
    const float* __restrict__ in,
    const float* __restrict__ w_in, const float* __restrict__ b_in,
    const _Float16* __restrict__ whf, const float* __restrict__ b_rec,
    const float* __restrict__ w_key, const float* __restrict__ b_key,
    const float* __restrict__ z,
    float* __restrict__ out)
{
    __shared__ __align__(16) _Float16 hsh16[HH];     // h_{t-1} fp16 (1 KB)
    __shared__ __align__(16) float pbuf[HH];         // K-half-1 partials (2 KB)
    __shared__ __align__(16) float tbuf[2][HH][17];  // hs 16-step tiles (68 KB)
    __shared__ __align__(16) float keysT[2][2][16];
    __shared__ __align__(16) float prsT[2][4][16];
    __shared__ __align__(16) float tmT[2][16];
    __shared__ float wi_sh[HH][6];
    __shared__ float bsum[HH];
    __shared__ float wk2[2][HH];
    __shared__ float inp6[8];
    __shared__ float kred[8][2];

    const int tid = threadIdx.x;
    const int bb  = blockIdx.x;            // one batch per block
    const int wv  = tid >> 6;              // 0..15
    const int ln  = tid & 63;
    const int row = tid & (HH - 1);        // output row
    const int kh  = tid >> 9;              // K-half (wave-uniform)
    const float* inb = in + (long)bb * 8 * TN;

    // ---------------- init ----------------
    if (tid < HH) {
        hsh16[tid] = (_Float16)0.0f;
        tbuf[0][tid][0] = 0.0f;
        bsum[tid]  = b_in[tid] + b_rec[tid];
        wk2[0][tid] = w_key[tid];
        wk2[1][tid] = w_key[HH + tid];
        #pragma unroll
        for (int c = 0; c < 6; ++c) wi_sh[tid][c] = w_in[tid * 6 + c];
    }
    if (tid < 256) {   // tm_modified[bb, 0, :] = tm1
        f32x4 v = *(const f32x4*)(inb + 6 * TN + tid * 4);
        __builtin_nontemporal_store(v, (f32x4*)(out + OFF_TM + (long)bb * 2 * TN + tid * 4));
    }
    if (tid == 0) {
        keysT[0][0][0] = 0.0f; keysT[0][1][0] = 0.0f;
        prsT[0][0][0] = 0.0f; prsT[0][1][0] = 0.0f;
        prsT[0][2][0] = 0.0f; prsT[0][3][0] = 0.0f;
        tmT[0][0] = inb[7 * TN];            // tm2[:,0]
    }
    // argmax(tm1) first-occurrence — wave 0 (thread 0 keeps result)
    int idxm = 0;
    if (wv == 0) {
        const float* tm1p = inb + 6 * TN;
        float bv = -3.0e38f; int bi = 0;
        for (int i = 0; i < 16; ++i) {
            int tt = i * 64 + ln;
            float v = tm1p[tt];
            if (v > bv) { bv = v; bi = tt; }
        }
        for (int m = 1; m < 64; m <<= 1) {
            float ov = __shfl_xor(bv, m);
            int   oi = __shfl_xor(bi, m);
            if (ov > bv || (ov == bv && oi < bi)) { bv = ov; bi = oi; }
        }
        idxm = bi;
    }

    // ---- load this thread's 256 weights into registers (held all kernel) ----
    uint4 wreg[32];
    {
        const _Float16* wp = whf + (long)row * HH + kh * 256;
        #pragma unroll
        for (int i = 0; i < 32; ++i) wreg[i] = *(const uint4*)(wp + i * 8);
    }

    float kh_key = 1.0f, off = 0.0f;       // thread-0 carries
    int side_pre = 1;
    __syncthreads();

    // ---------------- time loop ----------------
    for (int t = 1; t < TN; ++t) {
        const int tile = (t >> 4) & 1, sl = t & 15;

        // stage loads issued early (thread 0) — GEMV covers their latency
        float ld0=0,ld1=0,ld2=0,ld3=0,ld4=0,ld5=0,ld6=0,ld7=0, zld=0;
        if (tid == 0) {
            ld0 = inb[t];          ld1 = inb[TN + t];
            ld2 = inb[2 * TN + t]; ld3 = inb[3 * TN + t];
            ld4 = inb[4 * TN + t]; ld5 = inb[5 * TN + t];
            ld6 = inb[6 * TN + t]; ld7 = inb[7 * TN + t];
            zld = z[(long)(t - 1) * BB + bb];
        }

        // ---- GEMV partial: 128 dot2, 4 independent chains ----
        float p0 = 0.f, p1 = 0.f, p2 = 0.f, p3 = 0.f;
        const _Float16* hbase = hsh16 + kh * 256;   // wave-uniform → broadcast reads
        #pragma unroll
        for (int i = 0; i < 32; ++i) {
            const uint4 hu = *(const uint4*)(hbase + i * 8);
            p0 = dot2(wreg[i].x, hu.x, p0);
            p1 = dot2(wreg[i].y, hu.y, p1);
            p2 = dot2(wreg[i].z, hu.z, p2);
            p3 = dot2(wreg[i].w, hu.w, p3);
        }
        const float part = (p0 + p1) + (p2 + p3);
        if (tid >= HH) pbuf[row] = part;

        // ---- stage: keys of t-1, scalar chain, inp6 ----
        if (tid == 0) {
            if (t > 1) {
                float k0 = 0.f, k1 = 0.f;
                #pragma unroll
                for (int w = 0; w < 8; ++w) { k0 += kred[w][0]; k1 += kred[w][1]; }
                const float key0 = sigm(k0 + b_key[0]);
                const float key1 = sigm(k1 + b_key[1]);
                const int pt = t - 1;
                keysT[(pt >> 4) & 1][0][pt & 15] = key0;
                keysT[(pt >> 4) & 1][1][pt & 15] = key1;
                kh_key = key0;
            }
            const int side  = (kh_key > 0.5f);
            const float asum0 = ld2 * kh_key + ld4 * (1.0f - kh_key);
            const float asum1 = ld3 * kh_key + ld5 * (1.0f - kh_key);
            const int closer1  = (fabsf(ld0 - ld6) <= fabsf(ld1 - ld6));
            const int done     = (t > idxm);
            const int switched = ((side != side_pre) && done && (side != closer1));
            const float t2c = ld7 + off;
            if (switched) off += zld * fabsf(0.05f * t2c);
            const float t2e = ld7 + off;
            side_pre = side;
            float u0 = (ld6 - ld0) / (0.15f * ld0);     float pr10 = (ld6 == 0.0f) ? 0.0f : u0 * u0;
            float u1 = (ld6 - ld1) / (0.15f * ld1);     float pr11 = (ld6 == 0.0f) ? 0.0f : u1 * u1;
            float u2 = (t2e - asum0) / (0.15f * asum0); float pr20 = (t2e == 0.0f) ? 0.0f : u2 * u2;
            float u3 = (t2e - asum1) / (0.15f * asum1); float pr21 = (t2e == 0.0f) ? 0.0f : u3 * u3;
            prsT[tile][0][sl] = pr10; prsT[tile][1][sl] = pr11;
            prsT[tile][2][sl] = pr20; prsT[tile][3][sl] = pr21;
            tmT[tile][sl] = t2e;
            inp6[0] = ld0; inp6[1] = ld1; inp6[2] = asum0;
            inp6[3] = asum1; inp6[4] = ld6; inp6[5] = t2e;
        }
        __syncthreads();   // A: partials/inp6 visible; h-reads done

        if (tid < HH) {
            // ---- finalize row j = tid ----
            const int j = tid;
            float sm = part + pbuf[j] + bsum[j]
                     + wi_sh[j][0] * inp6[0] + wi_sh[j][1] * inp6[1] + wi_sh[j][2] * inp6[2]
                     + wi_sh[j][3] * inp6[3] + wi_sh[j][4] * inp6[4] + wi_sh[j][5] * inp6[5];
            const float h = tanhf(sm);
            hsh16[j] = (_Float16)h;
            tbuf[tile][j][sl] = h;
            float ka0 = h * wk2[0][j];
            float ka1 = h * wk2[1][j];
            #pragma unroll
            for (int m = 1; m < 64; m <<= 1) { ka0 += __shfl_xor(ka0, m); ka1 += __shfl_xor(ka1, m); }
            if (ln == 0) { kred[wv][0] = ka0; kred[wv][1] = ka1; }
        } else if ((t & 15) == 0) {
            // ---- waves 8-15: flush previous 16-step tile ----
            const int f = tile ^ 1;
            const int t0 = t - 16;
            const int i = tid - HH;          // 0..511
            if (i < 8) {
                const int ch = i >> 2, q4 = i & 3;
                __builtin_nontemporal_store(*(const f32x4*)&keysT[f][ch][q4 * 4],
                    (f32x4*)(out + OFF_KEYS + (long)bb * 2 * TN + ch * TN + t0 + q4 * 4));
            } else if (i < 24) {
                const int ix = i - 8, ch = ix >> 2, q4 = ix & 3;
                __builtin_nontemporal_store(*(const f32x4*)&prsT[f][ch][q4 * 4],
                    (f32x4*)(out + OFF_PRS + (long)bb * 4 * TN + ch * TN + t0 + q4 * 4));
            } else if (i < 28) {
                const int q4 = i - 24;
                __builtin_nontemporal_store(*(const f32x4*)&tmT[f][q4 * 4],
                    (f32x4*)(out + OFF_TM + (long)bb * 2 * TN + TN + t0 + q4 * 4));
            }
            const float* tr = &tbuf[f][i][0];
            #pragma unroll
            for (int c = 0; c < 4; ++c) {
                f32x4 v;
                v.x = tr[c * 4]; v.y = tr[c * 4 + 1]; v.z = tr[c * 4 + 2]; v.w = tr[c * 4 + 3];
                __builtin_nontemporal_store(v,
                    (f32x4*)(out + OFF_HS + ((long)bb * HH + i) * TN + t0 + c * 4));
            }
        }
        __syncthreads();   // D: hsh16/kred/tbuf visible for next step
    }

    // ---------------- epilogue: key_1023 + final tile flush ----------------
    if (tid == 0) {
        float k0 = 0.f, k1 = 0.f;
        #pragma unroll
        for (int w = 0; w < 8; ++w) { k0 += kred[w][0]; k1 += kred[w][1]; }
        keysT[1][0][15] = sigm(k0 + b_key[0]);
        keysT[1][1][15] = sigm(k1 + b_key[1]);
    }
    __syncthreads();
    if (tid >= HH) {
        const int f = 1, t0 = TN - 16;
        const int i = tid - HH;
        if (i < 8) {
            const int ch = i >> 2, q4 = i & 3;
            __builtin_nontemporal_store(*(const f32x4*)&keysT[f][ch][q4 * 4],
                (f32x4*)(out + OFF_KEYS + (long)bb * 2 * TN + ch * TN + t0 + q4 * 4));
        } else if (i < 24) {
            const int ix = i - 8, ch = ix >> 2, q4 = ix & 3;
            __builtin_nontemporal_store(*(const f32x4*)&prsT[f][ch][q4 * 4],
                (f32x4*)(out + OFF_PRS + (long)bb * 4 * TN + ch * TN + t0 + q4 * 4));
        } else if (i < 28) {
            const int q4 = i - 24;
            __builtin_nontemporal_store(*(const f32x4*)&tmT[f][q4 * 4],
                (f32x4*)(out + OFF_TM + (long)bb * 2 * TN + TN + t0 + q4 * 4));
        }
        const float* tr = &tbuf[f][i][0];
        #pragma unroll
        for (int c = 0; c < 4; ++c) {
            f32x4 v;
            v.x = tr[c * 4]; v.y = tr[c * 4 + 1]; v.z = tr[c * 4 + 2]; v.w = tr[c * 4 + 3];
            __builtin_nontemporal_store(v,
                (f32x4*)(out + OFF_HS + ((long)bb * HH + i) * TN + t0 + c * 4));
        }
    }
}

extern "C" void kernel_launch(void* const* d_in, const int* in_sizes, int n_in,
                              void* d_out, int out_size, void* d_ws, size_t ws_size,
                              hipStream_t stream) {
    (void)in_sizes; (void)n_in; (void)out_size; (void)ws_size;
    const float* in    = (const float*)d_in[0];
    const float* w_in  = (const float*)d_in[1];
    const float* b_in  = (const float*)d_in[2];
    const float* w_rec = (const float*)d_in[3];
    const float* b_rec = (const float*)d_in[4];
    const float* w_key = (const float*)d_in[5];
    const float* b_key = (const float*)d_in[6];
    const float* z     = (const float*)d_in[7];
    float* out = (float*)d_out;
    _Float16* whf = (_Float16*)d_ws;   // 512 KB scratch

    hipLaunchKernelGGL(conv_fp16, dim3(HH * HH / 1024), dim3(256), 0, stream, w_rec, whf);
    hipLaunchKernelGGL(rnn_fused, dim3(BB), dim3(NTHR), 0, stream,
                       in, w_in, b_in, whf, b_rec, w_key, b_key, z, out);
}